// Round 7
// baseline (156.671 us; speedup 1.0000x reference)
//
#include <hip/hip_runtime.h>
#include <cmath>
#include <cstdint>

#define BLOCK 256

// Constant-address-space float: uniform-index loads lower to s_load_* (SMEM,
// scalar pipe) instead of VALU readlane / LDS / VMEM broadcast.
typedef __attribute__((address_space(4))) const float cfloat;

// SoA table per batch: {x1[64], y1[64], x2[64], y2[64], area[64]} = 320 floats.
__global__ void ainno_pre(const float* __restrict__ gt, float* __restrict__ tab,
                          int B, int K) {
    int i = blockIdx.x * blockDim.x + threadIdx.x;
    if (i < B * K) {
        int b = i / K, k = i - b * K;
        float4 g = ((const float4*)gt)[i];
        float x2 = g.x + g.z, y2 = g.y + g.w;   // same arithmetic as reference
        float* t = tab + (size_t)b * 5 * K;
        t[0 * K + k] = g.x;
        t[1 * K + k] = g.y;
        t[2 * K + k] = x2;
        t[3 * K + k] = y2;
        t[4 * K + k] = (x2 - g.x) * (y2 - g.y);
    }
}

// acc layout: per batch b, 4 floats [pos_count, stc_sum, str_sum, pad];
// acc[4*B] (as int) is the block-completion counter. Zeroed by memsetAsync.
__global__ void __launch_bounds__(BLOCK, 8) ainno_main(
    const float* __restrict__ ss,       // (B, A, 6)
    const float* __restrict__ anchors,  // (A, 4) xywh
    const float* __restrict__ gt,       // (B, K, 4) xywh
    const float* __restrict__ tab,      // (B, 5, 64) SoA box table
    float* __restrict__ acc,
    float* __restrict__ out,
    int A, int K, int B)
{
    __shared__ float red[(BLOCK / 64) * 3];
    const int b    = blockIdx.y;
    const int tid  = threadIdx.x;
    const int lane = tid & 63;
    const int a    = blockIdx.x * BLOCK + tid;
    const int ac   = a < A ? a : A - 1;          // clamp; contribution guarded

    // Prefetch logit before the k-loop: HBM latency hides under ~1100 VALU ops.
    const float* sp = ss + ((size_t)b * A + ac) * 6;
    float logit = sp[4];

    float4 an = ((const float4*)anchors)[ac];
    float ax  = an.x,        ay  = an.y;
    float axx = an.x + an.z, ayy = an.y + an.w;
    float aar = (axx - ax) * (ayy - ay);

    // Uniform pointer + uniform loop index + constant AS -> s_load (scalar
    // pipe, free broadcast into SGPRs; VALU reads them as SGPR operands).
    const float* tb = tab + (size_t)b * 320;
    cfloat* tx1 = (cfloat*)(uintptr_t)(tb);
    cfloat* ty1 = (cfloat*)(uintptr_t)(tb + 64);
    cfloat* tx2 = (cfloat*)(uintptr_t)(tb + 128);
    cfloat* ty2 = (cfloat*)(uintptr_t)(tb + 192);
    cfloat* tar = (cfloat*)(uintptr_t)(tb + 256);

    // Cross-multiplied linear argmax (strict > keeps first max, matching
    // jnp.argmax). One divide total, after the loop, with the exact operands
    // the reference divides -> bit-identical winning IoU.
    float bi = -1.f, bd = 1.f;
    int bk = 0;
    #pragma unroll 8
    for (int k = 0; k < 64; ++k) {
        float sx1 = tx1[k];
        float sy1 = ty1[k];
        float sx2 = tx2[k];
        float sy2 = ty2[k];
        float sar = tar[k];
        float w = fminf(axx, sx2) - fmaxf(ax, sx1);
        float h = fminf(ayy, sy2) - fmaxf(ay, sy1);
        w = fmaxf(w, 0.f); h = fmaxf(h, 0.f);
        float inter = w * h;
        float den = (aar + sar) - inter;
        bool better = inter * bd > bi * den;
        bi = better ? inter : bi;
        bd = better ? den   : bd;
        bk = better ? k     : bk;
    }

    float posf = 0.f, stcs = 0.f, strs = 0.f;
    {
        float score = bi / bd;                   // == ref max IoU (same operands)
        bool inb = a < A;
        bool pos = inb && (score >= 0.5f);
        bool neg = inb && (score < 0.4f);
        if (pos | neg) {
            float x = logit;
            float e = expf(-x);
            float p = 1.f / (1.f + e);
            if (pos) {
                posf = 1.f;
                float ce  = log1pf(e);           // softplus(-x) = -log_sigmoid(x)
                float omp = 1.f - p;
                stcs = 0.25f * ce * omp * omp;

                // rare path: reload winner GT box (divergent index, L1/L2 hit)
                float4 g = ((const float4*)(gt + (size_t)b * K * 4))[bk];
                float wx1 = g.x, wy1 = g.y;
                float wx2 = g.x + g.z, wy2 = g.y + g.w;
                float war = (wx2 - wx1) * (wy2 - wy1);

                float2 p01 = *(const float2*)(sp);
                float2 p23 = *(const float2*)(sp + 2);
                float px  = p01.x, py = p01.y;
                float pxx = px + p23.x, pyy = py + p23.y;
                float ew = fminf(pxx, wx2) - fmaxf(px, wx1);
                float eh = fminf(pyy, wy2) - fmaxf(py, wy1);
                ew = fmaxf(ew, 0.f); eh = fmaxf(eh, 0.f);
                float einter = ew * eh;
                float pa = (pxx - px) * (pyy - py);
                float eiou = einter / (pa + war - einter);
                strs = -logf(eiou + 0.01f);
            } else {
                float ce = log1pf(expf(x));      // softplus(x) = -log_sigmoid(-x)
                stcs = 0.75f * ce * p * p;
            }
        }
    }

    // wave64 shuffle reduction -> LDS across waves -> 3 atomics per block
    float v0 = posf, v1 = stcs, v2 = strs;
    for (int off = 32; off > 0; off >>= 1) {
        v0 += __shfl_down(v0, off, 64);
        v1 += __shfl_down(v1, off, 64);
        v2 += __shfl_down(v2, off, 64);
    }
    const int wave = tid >> 6;
    if (lane == 0) {
        red[wave * 3 + 0] = v0;
        red[wave * 3 + 1] = v1;
        red[wave * 3 + 2] = v2;
    }
    __syncthreads();
    if (tid == 0) {
        float s0 = 0.f, s1 = 0.f, s2 = 0.f;
        for (int w = 0; w < BLOCK / 64; ++w) {
            s0 += red[w * 3 + 0];
            s1 += red[w * 3 + 1];
            s2 += red[w * 3 + 2];
        }
        atomicAdd(&acc[b * 4 + 0], s0);
        atomicAdd(&acc[b * 4 + 1], s1);
        atomicAdd(&acc[b * 4 + 2], s2);
        __threadfence();
        int total = gridDim.x * gridDim.y;
        int old = atomicAdd((int*)(acc + 4 * B), 1);
        if (old == total - 1) {
            // last block finalizes; device-scope atomic reads avoid stale
            // per-XCD L2 lines
            float tot = 0.f;
            for (int bb = 0; bb < B; ++bb) {
                float pc = atomicAdd(&acc[bb * 4 + 0], 0.f);
                float st = atomicAdd(&acc[bb * 4 + 1], 0.f);
                float sr = atomicAdd(&acc[bb * 4 + 2], 0.f);
                float safe = pc > 0.f ? pc : 1.f;
                tot += st / safe;
                if (pc > 0.f) tot += sr / safe;
            }
            out[0] = tot / (float)B;
        }
    }
}

extern "C" void kernel_launch(void* const* d_in, const int* in_sizes, int n_in,
                              void* d_out, int out_size, void* d_ws, size_t ws_size,
                              hipStream_t stream) {
    const float* ss      = (const float*)d_in[0];
    const float* anchors = (const float*)d_in[1];
    const float* gt      = (const float*)d_in[2];
    float* out = (float*)d_out;
    float* acc = (float*)d_ws;                   // first 256 B: accumulators
    float* tab = (float*)((char*)d_ws + 256);    // 256B-aligned SoA table
    const int A = in_sizes[1] / 4;
    const int B = in_sizes[0] / (A * 6);
    const int K = in_sizes[2] / (B * 4);

    hipMemsetAsync(acc, 0, ((size_t)B * 4 + 1) * sizeof(float), stream);

    const int BK = B * K;
    ainno_pre<<<(BK + 255) / 256, 256, 0, stream>>>(gt, tab, B, K);

    dim3 grid((A + BLOCK - 1) / BLOCK, B);
    ainno_main<<<grid, BLOCK, 0, stream>>>(ss, anchors, gt, tab, acc, out, A, K, B);
}